// Round 1
// baseline (70.174 us; speedup 1.0000x reference)
//
#include <hip/hip_runtime.h>
#include <math.h>

// LSTM autoencoder, single timestep, h0=c0=0.
// => whh matrices unused; f-gate unused (f * c0 == 0).
// Each cell: gates = wih@x + bih + bhh; h = sigmoid(o)*tanh(sigmoid(i)*tanh(g))
// using rows j (i), j+2*dh (g), j+3*dh (o) of wih.

__device__ __forceinline__ float sigmoidf_(float v) {
    return 1.0f / (1.0f + expf(-v));
}

// One 64-lane wave per output element j. 4 waves / 256-thread block.
template<int C>
__global__ __launch_bounds__(256)
void lstm_cell_k(const float* __restrict__ wih,
                 const float* __restrict__ bih,
                 const float* __restrict__ bhh,
                 const float* __restrict__ x,
                 float* __restrict__ h,
                 int dh)
{
    const int lane = threadIdx.x & 63;
    const int j = blockIdx.x * 4 + (threadIdx.x >> 6);
    if (j >= dh) return;

    const float* __restrict__ wi = wih + (size_t)j * C;
    const float* __restrict__ wg = wih + ((size_t)j + 2u * (size_t)dh) * C;
    const float* __restrict__ wo = wih + ((size_t)j + 3u * (size_t)dh) * C;

    float si = 0.f, sg = 0.f, so = 0.f;
    #pragma unroll 4
    for (int c0 = 0; c0 < C; c0 += 256) {
        const int c = c0 + lane * 4;
        const float4 xv = *reinterpret_cast<const float4*>(x + c);
        const float4 av = *reinterpret_cast<const float4*>(wi + c);
        const float4 gv = *reinterpret_cast<const float4*>(wg + c);
        const float4 ov = *reinterpret_cast<const float4*>(wo + c);
        si += av.x * xv.x + av.y * xv.y + av.z * xv.z + av.w * xv.w;
        sg += gv.x * xv.x + gv.y * xv.y + gv.z * xv.z + gv.w * xv.w;
        so += ov.x * xv.x + ov.y * xv.y + ov.z * xv.z + ov.w * xv.w;
    }

    #pragma unroll
    for (int off = 32; off > 0; off >>= 1) {
        si += __shfl_xor(si, off, 64);
        sg += __shfl_xor(sg, off, 64);
        so += __shfl_xor(so, off, 64);
    }

    if (lane == 0) {
        const float gi = si + bih[j]          + bhh[j];
        const float gg = sg + bih[j + 2 * dh] + bhh[j + 2 * dh];
        const float go = so + bih[j + 3 * dh] + bhh[j + 3 * dh];
        const float cc = sigmoidf_(gi) * tanhf(gg);
        h[j] = sigmoidf_(go) * tanhf(cc);
    }
}

// y = W@x + b, one wave per row.
template<int C>
__global__ __launch_bounds__(256)
void linear_k(const float* __restrict__ w,
              const float* __restrict__ b,
              const float* __restrict__ x,
              float* __restrict__ y,
              int R)
{
    const int lane = threadIdx.x & 63;
    const int j = blockIdx.x * 4 + (threadIdx.x >> 6);
    if (j >= R) return;

    const float* __restrict__ wr = w + (size_t)j * C;
    float s = 0.f;
    #pragma unroll 4
    for (int c0 = 0; c0 < C; c0 += 256) {
        const int c = c0 + lane * 4;
        const float4 xv = *reinterpret_cast<const float4*>(x + c);
        const float4 wv = *reinterpret_cast<const float4*>(wr + c);
        s += wv.x * xv.x + wv.y * xv.y + wv.z * xv.z + wv.w * xv.w;
    }
    #pragma unroll
    for (int off = 32; off > 0; off >>= 1) s += __shfl_xor(s, off, 64);
    if (lane == 0) y[j] = s + b[j];
}

extern "C" void kernel_launch(void* const* d_in, const int* in_sizes, int n_in,
                              void* d_out, int out_size, void* d_ws, size_t ws_size,
                              hipStream_t stream)
{
    // setup_inputs() order:
    // 0:x 1-4:e1l0(wih,whh,bih,bhh) 5-8:e1l1 9-12:e2 13-16:d1l0 17-20:d1l1
    // 21-24:d2 25:out_w 26:out_b
    const float* x        = (const float*)d_in[0];
    const float* e1l0_wih = (const float*)d_in[1];
    const float* e1l0_bih = (const float*)d_in[3];
    const float* e1l0_bhh = (const float*)d_in[4];
    const float* e1l1_wih = (const float*)d_in[5];
    const float* e1l1_bih = (const float*)d_in[7];
    const float* e1l1_bhh = (const float*)d_in[8];
    const float* e2_wih   = (const float*)d_in[9];
    const float* e2_bih   = (const float*)d_in[11];
    const float* e2_bhh   = (const float*)d_in[12];
    const float* d1l0_wih = (const float*)d_in[13];
    const float* d1l0_bih = (const float*)d_in[15];
    const float* d1l0_bhh = (const float*)d_in[16];
    const float* d1l1_wih = (const float*)d_in[17];
    const float* d1l1_bih = (const float*)d_in[19];
    const float* d1l1_bhh = (const float*)d_in[20];
    const float* d2_wih   = (const float*)d_in[21];
    const float* d2_bih   = (const float*)d_in[23];
    const float* d2_bhh   = (const float*)d_in[24];
    const float* out_w    = (const float*)d_in[25];
    const float* out_b    = (const float*)d_in[26];
    float* out = (float*)d_out;

    float* ws = (float*)d_ws;
    float* h1 = ws;           // 2048
    float* h2 = ws + 2048;    // 2048
    float* z  = ws + 4096;    // 1024
    float* h3 = ws + 5120;    // 1024
    float* h4 = ws + 6144;    // 1024
    float* h5 = ws + 7168;    // 2048

    // Encoder
    lstm_cell_k<4096><<<512, 256, 0, stream>>>(e1l0_wih, e1l0_bih, e1l0_bhh, x,  h1, 2048);
    lstm_cell_k<2048><<<512, 256, 0, stream>>>(e1l1_wih, e1l1_bih, e1l1_bhh, h1, h2, 2048);
    lstm_cell_k<2048><<<256, 256, 0, stream>>>(e2_wih,   e2_bih,   e2_bhh,   h2, z,  1024);
    // Decoder
    lstm_cell_k<1024><<<256, 256, 0, stream>>>(d1l0_wih, d1l0_bih, d1l0_bhh, z,  h3, 1024);
    lstm_cell_k<1024><<<256, 256, 0, stream>>>(d1l1_wih, d1l1_bih, d1l1_bhh, h3, h4, 1024);
    lstm_cell_k<1024><<<512, 256, 0, stream>>>(d2_wih,   d2_bih,   d2_bhh,   h4, h5, 2048);
    // Output projection
    linear_k<2048><<<1024, 256, 0, stream>>>(out_w, out_b, h5, out, 4096);
}